// Round 1
// baseline (31232.303 us; speedup 1.0000x reference)
//
#include <hip/hip_runtime.h>
#include <hip/hip_fp16.h>

// TanhFixedPointLayer: z_{k+1} = tanh(z_k @ W^T + x), z0 = 0, 50 iterations.
// Fused persistent-tile design: each block owns 64 rows; z lives in LDS (f16),
// x lives in registers (fp32, C-layout), W streamed from L2 as f16 every iter.

#define DDIM 512
#define MTILE 64
#define NITER 50            // total iterations (z1 = tanh(x) counts as #1)

typedef _Float16 half8 __attribute__((ext_vector_type(8)));
typedef _Float16 half4v __attribute__((ext_vector_type(4)));
typedef float float4v __attribute__((ext_vector_type(4)));

__device__ __forceinline__ float fast_tanh(float t) {
    // tanh(t) = 1 - 2/(exp(2t)+1); exp(2t) = 2^(t*2*log2(e))
    float e = __builtin_amdgcn_exp2f(t * 2.8853900817779268f);
    return 1.0f - 2.0f * __builtin_amdgcn_rcpf(e + 1.0f);
}

// ---- prep: W fp32 -> f16 (ws). 512*512 elems, 4 per thread as float4.
__global__ void wconv_kernel(const float* __restrict__ W, _Float16* __restrict__ Wh) {
    int i = blockIdx.x * blockDim.x + threadIdx.x;   // 0..65535
    float4 w = ((const float4*)W)[i];
    half4v h;
    h[0] = (_Float16)w.x; h[1] = (_Float16)w.y;
    h[2] = (_Float16)w.z; h[3] = (_Float16)w.w;
    ((half4v*)Wh)[i] = h;
}

// LDS half-index with XOR swizzle on 16B (8-half) granules.
// Breaks the row-stride-1024B bank aliasing for ds_read_b128 A-frag loads.
__device__ __forceinline__ int zidx(int row, int col) {
    int g = col >> 3;
    int c = col & 7;
    return row * DDIM + (((g ^ (row & 7)) << 3) | c);
}

__global__ __launch_bounds__(512, 2)
void fixpoint_kernel(const float* __restrict__ x,
                     const _Float16* __restrict__ Wh,
                     float* __restrict__ out) {
    __shared__ _Float16 zsh[MTILE * DDIM];   // 64 KB exactly

    const int tid  = threadIdx.x;
    const int lane = tid & 63;
    const int wid  = tid >> 6;     // 0..7
    const int wm   = wid & 3;      // m-tile (16 rows each) -> 4 m-waves share B-frags
    const int wn   = wid >> 2;     // n-half (256 cols each)
    const int l15  = lane & 15;
    const int quad = lane >> 4;    // 0..3

    const int row_blk  = blockIdx.x * MTILE;
    const int col_base = wn * 256 + l15;        // + nt*16
    const int row_base = wm * 16 + quad * 4;    // + r   (local row in tile)

    // ---- x in registers, at this lane's C/D accumulator positions
    float xr[16][4];
#pragma unroll
    for (int nt = 0; nt < 16; ++nt) {
#pragma unroll
        for (int r = 0; r < 4; ++r) {
            xr[nt][r] = x[(size_t)(row_blk + row_base + r) * DDIM + (col_base + nt * 16)];
        }
    }

    // ---- z1 = tanh(x) -> LDS
#pragma unroll
    for (int nt = 0; nt < 16; ++nt) {
#pragma unroll
        for (int r = 0; r < 4; ++r) {
            zsh[zidx(row_base + r, col_base + nt * 16)] = (_Float16)fast_tanh(xr[nt][r]);
        }
    }
    __syncthreads();

    // B-frag base: W[n][k], n = wn*256 + nt*16 + l15, k = ks*32 + quad*8
    // (W row-major IS the B^T layout: lane's 8 k-values are 16B contiguous)
    const half8* wv = (const half8*)(Wh + ((size_t)(wn * 256 + l15) * DDIM) + quad * 8);
    // in half8 units: + nt*16*512/8 = nt*1024, + ks*32/8 = ks*4

    const int arow = wm * 16 + l15;   // A-frag row for this lane

    for (int it = 0; it < NITER - 1; ++it) {
        float4v acc[16];
#pragma unroll
        for (int nt = 0; nt < 16; ++nt) acc[nt] = (float4v){0.f, 0.f, 0.f, 0.f};

#pragma unroll
        for (int ks = 0; ks < 16; ++ks) {
            int k0 = ks * 32 + quad * 8;
            half8 a = *(const half8*)&zsh[zidx(arow, k0)];   // ds_read_b128
#pragma unroll
            for (int nt = 0; nt < 16; ++nt) {
                half8 b = wv[nt * 1024 + ks * 4];            // 16B from L2-resident W
                acc[nt] = __builtin_amdgcn_mfma_f32_16x16x32_f16(a, b, acc[nt], 0, 0, 0);
            }
        }
        __syncthreads();   // all A-frag reads of z_k complete

        // epilogue: z_{k+1} = tanh(acc + x) -> LDS (f16)
#pragma unroll
        for (int nt = 0; nt < 16; ++nt) {
#pragma unroll
            for (int r = 0; r < 4; ++r) {
                float v = fast_tanh(acc[nt][r] + xr[nt][r]);
                zsh[zidx(row_base + r, col_base + nt * 16)] = (_Float16)v;
            }
        }
        __syncthreads();
    }

    // ---- coalesced fp32 write-out from LDS: 64 rows x 64 granules of 8 floats
#pragma unroll
    for (int j = 0; j < 8; ++j) {
        int gid = j * 512 + tid;
        int row = gid >> 6;
        int g   = gid & 63;
        half8 h = *(const half8*)&zsh[row * DDIM + ((g ^ (row & 7)) << 3)];
        size_t o = (size_t)(row_blk + row) * DDIM + g * 8;
        float4 lo = { (float)h[0], (float)h[1], (float)h[2], (float)h[3] };
        float4 hi = { (float)h[4], (float)h[5], (float)h[6], (float)h[7] };
        *(float4*)(out + o)     = lo;
        *(float4*)(out + o + 4) = hi;
    }
}

extern "C" void kernel_launch(void* const* d_in, const int* in_sizes, int n_in,
                              void* d_out, int out_size, void* d_ws, size_t ws_size,
                              hipStream_t stream) {
    const float* x = (const float*)d_in[0];   // [65536, 512] fp32
    const float* W = (const float*)d_in[1];   // [512, 512] fp32
    _Float16* Wh = (_Float16*)d_ws;           // 512 KB f16 W
    float* out = (float*)d_out;

    wconv_kernel<<<256, 256, 0, stream>>>(W, Wh);
    fixpoint_kernel<<<65536 / MTILE, 512, 0, stream>>>(x, Wh, out);
}

// Round 2
// 3453.502 us; speedup vs baseline: 9.0437x; 9.0437x over previous
//
#include <hip/hip_runtime.h>
#include <hip/hip_fp16.h>

// TanhFixedPointLayer: z_{k+1} = tanh(z_k @ W^T + x), z0 = 0, 50 iterations.
// Fused persistent-tile: block owns 64 rows; z lives in LDS (f16, frag-packed);
// x and accumulators in registers; W pre-packed into MFMA A-frag order and
// streamed from L2 every iteration (512 KB/block-iter, no duplication).
// MFMA roles transposed: D[n][m] = sum_k W[n][k] * z[m][k]  (A=W, B=z), so
// C/D lanes hold 4 consecutive n = next iteration's k -> contiguous b64 LDS
// writes, and both A and B fragment loads are lane-linear 16B.

#define DDIM  512
#define MTILE 64
#define NITER 50     // z1 = tanh(x) counts as iteration 1; 49 MFMA iterations

typedef _Float16 half8  __attribute__((ext_vector_type(8)));
typedef _Float16 half4v __attribute__((ext_vector_type(4)));
typedef float    float4v __attribute__((ext_vector_type(4)));

__device__ __forceinline__ float fast_tanh(float t) {
    // tanh(t) = 1 - 2/(exp(2t)+1); exp(2t) = 2^(t*2*log2(e)); exact +-1 at sat.
    float e = __builtin_amdgcn_exp2f(t * 2.8853900817779268f);
    return 1.0f - 2.0f * __builtin_amdgcn_rcpf(e + 1.0f);
}

// z LDS layout = frag-packed: element (m,k) at
//   ((k>>5)*4 + (m>>4))*512 + ((m&15) + 16*((k>>3)&3))*8 + (k&7)
// so B-frag (mf,ks) for lane L is the 16B chunk at ((ks*4+mf)*64 + L)*8.
__device__ __forceinline__ int zaddr(int m, int k) {
    return (((k >> 5) * 4 + (m >> 4)) << 9) + (((m & 15) + (((k >> 3) & 3) << 4)) << 3) + (k & 7);
}

// ---- prep: pack W (fp32 [512][512]) into f16 MFMA A-frag order.
// Frag (ks, nf) block = 64 lanes x 16B: lane L holds
//   W[nf*16 + (L&15)][ks*32 + (L>>4)*8 + j], j=0..7
__global__ void wpack_kernel(const float* __restrict__ W, _Float16* __restrict__ Wpk) {
    int gid  = blockIdx.x * blockDim.x + threadIdx.x;   // 0..32767
    int ks   = gid >> 11;
    int nf   = (gid >> 6) & 31;
    int lane = gid & 63;
    int row  = nf * 16 + (lane & 15);
    int col  = ks * 32 + (lane >> 4) * 8;
    const float* src = W + row * DDIM + col;
    half8 h;
#pragma unroll
    for (int j = 0; j < 8; ++j) h[j] = (_Float16)src[j];
    *(half8*)(Wpk + (size_t)gid * 8) = h;
}

__global__ __launch_bounds__(512, 2)
void fixpoint_kernel(const float* __restrict__ x,
                     const _Float16* __restrict__ Wpk,
                     float* __restrict__ out) {
    __shared__ __align__(16) _Float16 zsh[MTILE * DDIM];   // 64 KB, frag-packed

    const int tid  = threadIdx.x;
    const int lane = tid & 63;
    const int wid  = tid >> 6;          // 0..7, each wave owns 64 n-columns
    const int l15  = lane & 15;
    const int quad = lane >> 4;
    const int nf0  = wid * 4;           // first of this wave's 4 n-frags

    const int row_blk = blockIdx.x * MTILE;
    const half8* Wv = (const half8*)Wpk;

    // ---- x in registers at this lane's C/D slots:
    // xr[f][mf][r] = x[mf*16+l15][(nf0+f)*16 + quad*4 + r]
    float4 xr[4][4];
#pragma unroll
    for (int f = 0; f < 4; ++f) {
        int n = (nf0 + f) * 16 + quad * 4;
#pragma unroll
        for (int mf = 0; mf < 4; ++mf) {
            xr[f][mf] = *(const float4*)(x + (size_t)(row_blk + mf * 16 + l15) * DDIM + n);
        }
    }

    // ---- z1 = tanh(x) -> LDS (b64 contiguous writes)
#pragma unroll
    for (int f = 0; f < 4; ++f) {
        int n = (nf0 + f) * 16 + quad * 4;
#pragma unroll
        for (int mf = 0; mf < 4; ++mf) {
            int m = mf * 16 + l15;
            half4v h;
            h[0] = (_Float16)fast_tanh(xr[f][mf].x);
            h[1] = (_Float16)fast_tanh(xr[f][mf].y);
            h[2] = (_Float16)fast_tanh(xr[f][mf].z);
            h[3] = (_Float16)fast_tanh(xr[f][mf].w);
            *(half4v*)(zsh + zaddr(m, n)) = h;
        }
    }
    __syncthreads();

    for (int it = 0; it < NITER - 1; ++it) {
        float4v acc[4][4];
#pragma unroll
        for (int f = 0; f < 4; ++f)
#pragma unroll
            for (int mf = 0; mf < 4; ++mf) acc[f][mf] = (float4v){0.f, 0.f, 0.f, 0.f};

        half8 a_cur[4], b_cur[4], a_nxt[4], b_nxt[4];
#pragma unroll
        for (int f = 0; f < 4; ++f) a_cur[f] = Wv[(nf0 + f) * 64 + lane];
#pragma unroll
        for (int mf = 0; mf < 4; ++mf) b_cur[mf] = *(const half8*)(zsh + (mf * 64 + lane) * 8);

#pragma unroll
        for (int ks = 0; ks < 16; ++ks) {
            if (ks < 15) {
#pragma unroll
                for (int f = 0; f < 4; ++f)
                    a_nxt[f] = Wv[((ks + 1) * 32 + nf0 + f) * 64 + lane];
#pragma unroll
                for (int mf = 0; mf < 4; ++mf)
                    b_nxt[mf] = *(const half8*)(zsh + (((ks + 1) * 4 + mf) * 64 + lane) * 8);
            }
#pragma unroll
            for (int f = 0; f < 4; ++f)
#pragma unroll
                for (int mf = 0; mf < 4; ++mf)
                    acc[f][mf] = __builtin_amdgcn_mfma_f32_16x16x32_f16(a_cur[f], b_cur[mf], acc[f][mf], 0, 0, 0);
            if (ks < 15) {
#pragma unroll
                for (int f = 0; f < 4; ++f)  a_cur[f]  = a_nxt[f];
#pragma unroll
                for (int mf = 0; mf < 4; ++mf) b_cur[mf] = b_nxt[mf];
            }
        }
        __syncthreads();   // all reads of z_k done

        if (it < NITER - 2) {
            // z_{k+1} = tanh(acc + x) -> LDS, contiguous b64 per frag
#pragma unroll
            for (int f = 0; f < 4; ++f) {
                int n = (nf0 + f) * 16 + quad * 4;
#pragma unroll
                for (int mf = 0; mf < 4; ++mf) {
                    int m = mf * 16 + l15;
                    half4v h;
                    h[0] = (_Float16)fast_tanh(acc[f][mf][0] + xr[f][mf].x);
                    h[1] = (_Float16)fast_tanh(acc[f][mf][1] + xr[f][mf].y);
                    h[2] = (_Float16)fast_tanh(acc[f][mf][2] + xr[f][mf].z);
                    h[3] = (_Float16)fast_tanh(acc[f][mf][3] + xr[f][mf].w);
                    *(half4v*)(zsh + zaddr(m, n)) = h;
                }
            }
            __syncthreads();
        } else {
            // final iteration: store z50 straight from registers (fp32)
#pragma unroll
            for (int f = 0; f < 4; ++f) {
                int n = (nf0 + f) * 16 + quad * 4;
#pragma unroll
                for (int mf = 0; mf < 4; ++mf) {
                    float4 v;
                    v.x = fast_tanh(acc[f][mf][0] + xr[f][mf].x);
                    v.y = fast_tanh(acc[f][mf][1] + xr[f][mf].y);
                    v.z = fast_tanh(acc[f][mf][2] + xr[f][mf].z);
                    v.w = fast_tanh(acc[f][mf][3] + xr[f][mf].w);
                    *(float4*)(out + (size_t)(row_blk + mf * 16 + l15) * DDIM + n) = v;
                }
            }
        }
    }
}

extern "C" void kernel_launch(void* const* d_in, const int* in_sizes, int n_in,
                              void* d_out, int out_size, void* d_ws, size_t ws_size,
                              hipStream_t stream) {
    const float* x = (const float*)d_in[0];   // [65536, 512] fp32
    const float* W = (const float*)d_in[1];   // [512, 512] fp32
    _Float16* Wpk = (_Float16*)d_ws;          // 512 KB packed f16 W
    float* out = (float*)d_out;

    wpack_kernel<<<128, 256, 0, stream>>>(W, Wpk);
    fixpoint_kernel<<<65536 / MTILE, 512, 0, stream>>>(x, Wpk, out);
}